// Round 4
// baseline (43620.612 us; speedup 1.0000x reference)
//
#include <hip/hip_runtime.h>
#include <hip/hip_fp16.h>
#include <math.h>

// LSTM_11089605558768: T=16384 sequential steps, H=512, IN=32, OUT=1.
// Persistent scan, 32 worker wgs x 512 threads.
//
// R10 (R8/R9 post-mortem): the v_mov "pin" makes wreg non-remat, so when
// regalloc declines to keep the array live it SPILLS to scratch and reloads
// every step. Scratch fits XCD L2 -> invisible to FETCH/WRITE except dirty
// evictions (R9: +192B/step/block WRITE). Reload = 139KB/block/step over
// ~128B/cy = +800cy/step = the R9 regression. Fix: hold weights in AGPRs
// via explicit v_accvgpr_write/read asm. Unified file on gfx950: 68 acc +
// ~50 arch << 256/wave at 2 waves/SIMD. Volatile asm reads (1-2cy each,
// ~+100cy/step) prevent CSE from recreating 68 live VGPRs; volatile writes
// prevent remat; AGPRs add no scheduler VGPR-pressure -> no spill motive.
// sched_barrier(0) fences keep poll/matvec/epilogue regions from merging
// into one pressure peak. Structure otherwise = R9 (proven logic, passed):
// 512 thr, lane=(gate,hi,kq) kq 0..7, wreg 68/thread, one barrier/step,
// all-lane epilogue, publish from 16 lanes. Polling = R6-proven verbatim.

#define T_STEPS 16384
#define IN_DIM  32
#define H_DIM   512
#define SLOTS   32
#define H_SLICE 16      // H_DIM / SLOTS
#define KTOT    544     // H_DIM + IN_DIM
#define CH      68      // KTOT / 8 (per kq lane)

typedef unsigned int uint32x4 __attribute__((ext_vector_type(4)));

#define SCHED_FENCE() __builtin_amdgcn_sched_barrier(0)

__device__ __forceinline__ float fast_sigmoid(float v) {
  return 1.0f / (1.0f + __expf(-v));
}
__device__ __forceinline__ float fast_tanh(float v) {
  return 2.0f / (1.0f + __expf(-2.0f * v)) - 1.0f;  // 2*sigmoid(2x)-1
}

// --- packet I/O (always LLC-coherent: sc0 sc1) -----------------------------
__device__ __forceinline__ void store_pkt(unsigned int* p, unsigned int v) {
  asm volatile("global_store_dword %0, %1, off sc0 sc1"
               :: "v"(p), "v"(v) : "memory");
}
__device__ __forceinline__ uint32x4 load_pkt4(const unsigned int* p) {
  uint32x4 r;
  asm volatile("global_load_dwordx4 %0, %1, off sc0 sc1\n\ts_waitcnt vmcnt(0)"
               : "=&v"(r) : "v"(p) : "memory");
  return r;
}
__device__ __forceinline__ float pkt_to_f(unsigned int v) {
  return __half2float(__ushort_as_half((unsigned short)(v & 0xFFFFu)));
}

__launch_bounds__(512, 1)
__global__ void lstm_scan_kernel(
    const float* __restrict__ x,     // [T, 32]
    const float* __restrict__ Wih,   // [2048, 32]
    const float* __restrict__ Whh,   // [2048, 512]
    const float* __restrict__ bih,   // [2048]
    const float* __restrict__ bhh,   // [2048]
    const float* __restrict__ Wlin,  // [512]
    const float* __restrict__ blin,  // [1]
    float* __restrict__ out,         // [1]
    unsigned int* pub)               // [2][512] 4B packets (d_ws)
{
  const int slot = blockIdx.x;       // 0..31
  const int tid  = threadIdx.x;      // 0..511
  const int w    = tid >> 6;         // wave 0..7 -> owns h elements w*2, w*2+1
  const int l    = tid & 63;

  const int gate = l >> 4;
  const int hi   = (l >> 3) & 1;
  const int kq   = l & 7;

  // parity-double-buffered staging: [parity][0,512)=h(t), [512,544)=x_t
  __shared__ __align__(16) float buf[2][KTOT];
  __shared__ float red[256];          // final projection only

  const int R = gate * H_DIM + slot * H_SLICE + w * 2 + hi;  // global gate row

  // Persistent weight slice -> AGPRs (explicit accvgpr moves; non-remat,
  // zero VGPR pressure, no spill motive).
  float aw[CH];
  #pragma unroll
  for (int j = 0; j < CH; ++j) {
    const int k = kq * CH + j;
    const float wv = (k < H_DIM) ? Whh[R * H_DIM + k]
                                 : Wih[R * IN_DIM + (k - H_DIM)];
    asm volatile("v_accvgpr_write_b32 %0, %1" : "=a"(aw[j]) : "v"(wv));
  }
  SCHED_FENCE();

  const float bias = bih[R] + bhh[R];
  float c = 0.0f;  // cell state for h element slot*16+w*2+hi (replicated x32)

  // Polling assignment (R6-proven): tid<128 polls packets [4*tid, 4*tid+4);
  // own-slot group skipped (publishers provide it in fp32).
  const bool poller = (tid < 128) && ((tid >> 2) != slot);
  const bool xthr   = (tid < IN_DIM);

  if (tid < H_SLICE) buf[0][slot * H_SLICE + tid] = 0.0f;  // h(0) own slice

  #pragma unroll 1
  for (int t = 0; t < T_STEPS; ++t) {
    // x_t load overlaps the poll (independent; consumed after poll resolves)
    float xv = xthr ? x[t * IN_DIM + tid] : 0.0f;

    // ---- gather h(t): blind poll, 4 self-validating packets per thread ----
    if (poller) {
      const unsigned int* p = pub + (t & 1) * H_DIM + tid * 4;
      const unsigned int tg = (unsigned int)t & 0xFFFFu;
      uint32x4 r;
      for (;;) {
        r = load_pkt4(p);
        if ((r.x >> 16) == tg && (r.y >> 16) == tg &&
            (r.z >> 16) == tg && (r.w >> 16) == tg) break;
      }
      float4 hv4;
      hv4.x = pkt_to_f(r.x);
      hv4.y = pkt_to_f(r.y);
      hv4.z = pkt_to_f(r.z);
      hv4.w = pkt_to_f(r.w);
      *(float4*)(&buf[t & 1][tid * 4]) = hv4;  // contiguous: 0 bank conflicts
    }
    if (xthr) buf[t & 1][H_DIM + tid] = xv;
    SCHED_FENCE();
    __syncthreads();  // barrier B: h(t) + x_t staged (the only per-step barrier)
    SCHED_FENCE();

    // ---- matvec: lane covers row (gate,hi), k in [kq*68, kq*68+68) ----
    // float4 bases kq*272B: 8 distinct bank quads, same-kq lanes broadcast.
    const float4* hv = (const float4*)(&buf[t & 1][kq * CH]);
    float a0 = 0.f, a1 = 0.f, a2 = 0.f, a3 = 0.f;
    #pragma unroll
    for (int q = 0; q < CH / 4; ++q) {
      const float4 h4 = hv[q];
      float w0, w1, w2, w3;
      asm volatile("v_accvgpr_read_b32 %0, %1" : "=v"(w0) : "a"(aw[4 * q + 0]));
      asm volatile("v_accvgpr_read_b32 %0, %1" : "=v"(w1) : "a"(aw[4 * q + 1]));
      asm volatile("v_accvgpr_read_b32 %0, %1" : "=v"(w2) : "a"(aw[4 * q + 2]));
      asm volatile("v_accvgpr_read_b32 %0, %1" : "=v"(w3) : "a"(aw[4 * q + 3]));
      a0 = fmaf(w0, h4.x, a0);
      a1 = fmaf(w1, h4.y, a1);
      a2 = fmaf(w2, h4.z, a2);
      a3 = fmaf(w3, h4.w, a3);
    }
    SCHED_FENCE();
    float s = (a0 + a1) + (a2 + a3);
    s += __shfl_xor(s, 1, 64);   // reduce over kq (8-lane groups)
    s += __shfl_xor(s, 2, 64);
    s += __shfl_xor(s, 4, 64);
    const float g = s + bias;
    const float act = (gate == 2) ? fast_tanh(g) : fast_sigmoid(g);

    // gather i,f,g,o for this lane's hi (act replicated across kq)
    const int base = l & 15;     // hi*8 + kq
    const float ig = __shfl(act, base,      64);
    const float fg = __shfl(act, base + 16, 64);
    const float gt = __shfl(act, base + 32, 64);
    const float og = __shfl(act, base + 48, 64);
    c = fg * c + ig * gt;
    const float h = og * fast_tanh(c);
    SCHED_FENCE();

    // ---- publish: lanes (gate==0, kq==0), 2 per wave, all waves parallel ----
    if (gate == 0 && kq == 0) {
      const int hidx = slot * H_SLICE + w * 2 + hi;
      buf[(t + 1) & 1][hidx] = h;  // own-slice fp32 shortcut for next step
      const unsigned int pkt =
          (((unsigned int)(t + 1) & 0xFFFFu) << 16) |
          (unsigned int)__half_as_ushort(__float2half_rn(h));
      store_pkt(pub + ((t + 1) & 1) * H_DIM + hidx, pkt);
    }
    SCHED_FENCE();
    // Parity hazards: parity-(t+1) writers (publish fp32 + next poll staging)
    // are separated from parity-(t+1) readers of step t-1 by barrier B(t);
    // parity-(t&1) rewrites at t+2 are separated from matvec-t reads by
    // barrier B(t+1). Single barrier per step suffices (validated R8/R9).
  }

  // ---- slot 0: final projection out = h(T) . Wlin + blin ----
  if (slot != 0) return;
  if (poller) {  // gather h(T) (parity T&1 == 0); own slice already fp32
    const unsigned int* p = pub + (T_STEPS & 1) * H_DIM + tid * 4;
    const unsigned int tg = (unsigned int)T_STEPS & 0xFFFFu;
    uint32x4 r;
    for (;;) {
      r = load_pkt4(p);
      if ((r.x >> 16) == tg && (r.y >> 16) == tg &&
          (r.z >> 16) == tg && (r.w >> 16) == tg) break;
    }
    float4 hv4;
    hv4.x = pkt_to_f(r.x);
    hv4.y = pkt_to_f(r.y);
    hv4.z = pkt_to_f(r.z);
    hv4.w = pkt_to_f(r.w);
    *(float4*)(&buf[0][tid * 4]) = hv4;
  }
  __syncthreads();
  if (tid < 256)
    red[tid] = buf[0][2 * tid] * Wlin[2 * tid] +
               buf[0][2 * tid + 1] * Wlin[2 * tid + 1];
  __syncthreads();
  if (w == 0) {
    float s2 = red[l] + red[64 + l] + red[128 + l] + red[192 + l];
    #pragma unroll
    for (int off = 32; off > 0; off >>= 1) s2 += __shfl_down(s2, off, 64);
    if (l == 0) out[0] = s2 + blin[0];
  }
}

extern "C" void kernel_launch(void* const* d_in, const int* in_sizes, int n_in,
                              void* d_out, int out_size, void* d_ws, size_t ws_size,
                              hipStream_t stream) {
  const float* x    = (const float*)d_in[0];
  const float* Wih  = (const float*)d_in[1];
  const float* Whh  = (const float*)d_in[2];
  const float* bih  = (const float*)d_in[3];
  const float* bhh  = (const float*)d_in[4];
  const float* Wlin = (const float*)d_in[5];
  const float* blin = (const float*)d_in[6];
  float* out = (float*)d_out;

  unsigned int* pub = (unsigned int*)d_ws;  // [2][512] u32 = 4096 B

  // d_ws re-poisoned before every timed call; zeroed pub encodes
  // (tag=0, h=0) == the initial hidden state h(0).
  hipMemsetAsync(d_ws, 0, 4096, stream);
  hipLaunchKernelGGL(lstm_scan_kernel, dim3(SLOTS), dim3(512), 0, stream,
                     x, Wih, Whh, bih, bhh, Wlin, blin, out, pub);
}

// Round 6
// 29907.407 us; speedup vs baseline: 1.4585x; 1.4585x over previous
//
#include <hip/hip_runtime.h>
#include <hip/hip_fp16.h>
#include <math.h>

// LSTM_11089605558768: T=16384 sequential steps, H=512, IN=32, OUT=1.
// Persistent scan, 32 worker wgs x 256 threads; each wg owns 16 h-elements
// (64 gate rows x 544 k, [W_hh | W_ih] folded).
//
// R12 = R6 (proven 28.6ms; VGPR=144, weight pin HELD) + hang-proof dual-probe
// poll. R11's bench died in the harness (Trio ExceptionGroup, no counters);
// design audit found no hang mode (parity rule: tags at parity-q are = q mod 2,
// so a stale dangler can never false-validate the next step), but R12 hardens
// anyway: ping-pong loop is BOUNDED (2048 iters) with fallback to the
// R6-proven blind vmcnt(0) probe, and s_sleep is dropped (steady-state
// self-staggers: P = L - P + c -> P ~= L/2).
//  - Ping-pong: issue A; loop { issue B + vmcnt(1) -> A landed -> check;
//    issue A' + vmcnt(1) -> B landed -> check }. Sampling period ~L/2 vs
//    R6's L; mean discovery improves ~L/4 ~= 160cy of the 1745cy step.
//    Losers dangle across steps (oldest-first retirement + parity rule
//    make this safe); one vmcnt(0) after the t-loop.
//  - x_t staged by wave 2 (idle during poll): pollers' vmcnt stream pure.
//  - Loop body otherwise BYTE-IDENTICAL to R6 (R7-R10: any reshape makes
//    hipcc demote wreg[] to scratch; VGPR 96/88/64/52, WRITE 2x, +800cy/step).

#define T_STEPS 16384
#define IN_DIM  32
#define H_DIM   512
#define SLOTS   32
#define H_SLICE 16      // H_DIM / SLOTS
#define KTOT    544     // H_DIM + IN_DIM
#define CHUNK   136     // KTOT / 4 waves

typedef unsigned int uint32x4 __attribute__((ext_vector_type(4)));

__device__ __forceinline__ float fast_sigmoid(float v) {
  return 1.0f / (1.0f + __expf(-v));
}
__device__ __forceinline__ float fast_tanh(float v) {
  return 2.0f / (1.0f + __expf(-2.0f * v)) - 1.0f;  // 2*sigmoid(2x)-1
}

// --- packet I/O (always LLC-coherent: sc0 sc1) -----------------------------
__device__ __forceinline__ void store_pkt(unsigned int* p, unsigned int v) {
  asm volatile("global_store_dword %0, %1, off sc0 sc1"
               :: "v"(p), "v"(v) : "memory");
}
__device__ __forceinline__ uint32x4 load_pkt4(const unsigned int* p) {
  uint32x4 r;
  asm volatile("global_load_dwordx4 %0, %1, off sc0 sc1\n\ts_waitcnt vmcnt(0)"
               : "=&v"(r) : "v"(p) : "memory");
  return r;
}
__device__ __forceinline__ float pkt_to_f(unsigned int v) {
  return __half2float(__ushort_as_half((unsigned short)(v & 0xFFFFu)));
}
__device__ __forceinline__ bool tag_ok(const uint32x4& r, unsigned int tg) {
  return (r.x >> 16) == tg && (r.y >> 16) == tg &&
         (r.z >> 16) == tg && (r.w >> 16) == tg;
}
__device__ __forceinline__ void stage4(float* dst, const uint32x4& r) {
  float4 hv4;
  hv4.x = pkt_to_f(r.x);
  hv4.y = pkt_to_f(r.y);
  hv4.z = pkt_to_f(r.z);
  hv4.w = pkt_to_f(r.w);
  *(float4*)dst = hv4;  // contiguous float4: 0 bank conflicts (R6-proven)
}

__launch_bounds__(256, 1)
__global__ void lstm_scan_kernel(
    const float* __restrict__ x,     // [T, 32]
    const float* __restrict__ Wih,   // [2048, 32]
    const float* __restrict__ Whh,   // [2048, 512]
    const float* __restrict__ bih,   // [2048]
    const float* __restrict__ bhh,   // [2048]
    const float* __restrict__ Wlin,  // [512]
    const float* __restrict__ blin,  // [1]
    float* __restrict__ out,         // [1]
    unsigned int* pub)               // [2][512] 4B packets (d_ws)
{
  const int slot = blockIdx.x;       // 0..31
  const int tid  = threadIdx.x;
  const int w    = tid >> 6;   // wave 0..3 -> k-chunk
  const int l    = tid & 63;   // lane -> local gate row

  __shared__ __align__(16) float hshm[KTOT];  // [0,512)=h(t), [512,544)=x_t
  __shared__ float red[256];                  // per-wave partials

  // local row l: 0..15 = i, 16..31 = f, 32..47 = g, 48..63 = o
  const int R = (l >> 4) * H_DIM + slot * H_SLICE + (l & 15);

  // Persistent weight slice -> registers, then PIN with opaque asm identity
  // so the compiler cannot rematerialize the loads inside the t-loop.
  float wreg[CHUNK];
  #pragma unroll
  for (int j = 0; j < CHUNK; ++j) {
    const int k = w * CHUNK + j;
    wreg[j] = (k < H_DIM) ? Whh[R * H_DIM + k]
                          : Wih[R * IN_DIM + (k - H_DIM)];
  }
  #pragma unroll
  for (int j = 0; j < CHUNK; ++j)
    asm volatile("v_mov_b32 %0, %0" : "+v"(wreg[j]));

  const float bias = (w == 0) ? (bih[R] + bhh[R]) : 0.0f;

  float c = 0.0f;  // cell state: wave 0, lanes 0..15 (h index slot*16 + l)

  // Polling assignment (R6-proven): tid<128 polls packets [4*tid, 4*tid+4);
  // own-slot group skipped (wave-0 epilogue provides it in fp32).
  const bool poller = (tid < 128) && ((tid >> 2) != slot);
  const bool xthr   = (tid >= 128) && (tid < 128 + IN_DIM);  // wave 2 stages x
  if (tid < H_SLICE) hshm[slot * H_SLICE + tid] = 0.0f;  // h(0) own slice

  // Dual-probe registers: loop-carried (live across the t-loop) so their
  // physical regs stay reserved under pending dangling writebacks. Parity
  // rule makes stale dangler data un-validatable at the next step.
  uint32x4 rA = {0, 0, 0, 0}, rB = {0, 0, 0, 0};

  for (int t = 0; t < T_STEPS; ++t) {
    // ---- gather h(t): ping-pong dual probe, bounded, with blind fallback ---
    if (poller) {
      const unsigned int* p = pub + (t & 1) * H_DIM + tid * 4;
      const unsigned int tg = (unsigned int)t & 0xFFFFu;
      bool done = false;
      asm volatile("global_load_dwordx4 %0, %2, off sc0 sc1"
                   : "+v"(rA), "+v"(rB) : "v"(p) : "memory");
      #pragma unroll 1
      for (int it = 0; it < 2048; ++it) {
        // issue B; wait until only it may remain -> A (and all older
        // ops: danglers, publish store) retired
        asm volatile("global_load_dwordx4 %1, %2, off sc0 sc1\n\t"
                     "s_waitcnt vmcnt(1)"
                     : "+v"(rA), "+v"(rB) : "v"(p) : "memory");
        if (tag_ok(rA, tg)) {            // B left dangling
          stage4(hshm + tid * 4, rA);
          done = true; break;
        }
        // issue A'; wait -> B retired
        asm volatile("global_load_dwordx4 %0, %2, off sc0 sc1\n\t"
                     "s_waitcnt vmcnt(1)"
                     : "+v"(rA), "+v"(rB) : "v"(p) : "memory");
        if (tag_ok(rB, tg)) {            // A' left dangling
          stage4(hshm + tid * 4, rB);
          done = true; break;
        }
      }
      if (!done) {
        // hang-proof fallback: R6-proven blind probe (fresh regs; rA/rB
        // remain live so pending danglers cannot corrupt other values).
        for (;;) {
          uint32x4 r = load_pkt4(p);
          if (tag_ok(r, tg)) { stage4(hshm + tid * 4, r); break; }
        }
      }
    }
    if (xthr) hshm[H_DIM + (tid - 128)] = x[t * IN_DIM + (tid - 128)];
    __syncthreads();  // barrier B: h(t) + x_t staged

    // ---- matvec: thread (w,l) covers row l, k in [w*136, w*136+136) ----
    const float4* hv = (const float4*)(hshm + w * CHUNK);  // 544B-aligned
    float a0 = 0.f, a1 = 0.f, a2 = 0.f, a3 = 0.f;
    #pragma unroll
    for (int q = 0; q < CHUNK / 4; ++q) {
      const float4 h4 = hv[q];  // wave-uniform broadcast read
      a0 = fmaf(wreg[4 * q + 0], h4.x, a0);
      a1 = fmaf(wreg[4 * q + 1], h4.y, a1);
      a2 = fmaf(wreg[4 * q + 2], h4.z, a2);
      a3 = fmaf(wreg[4 * q + 3], h4.w, a3);
    }
    red[w * 64 + l] = (a0 + a1) + (a2 + a3);
    __syncthreads();  // barrier C: partials ready

    // ---- wave 0: activate (all 64 lanes in parallel), update, publish ----
    if (w == 0) {
      const float g = bias + red[l] + red[64 + l] + red[128 + l] + red[192 + l];
      // lanes 0-15: i (sig), 16-31: f (sig), 32-47: g (tanh), 48-63: o (sig)
      const float act = (l < 32 || l >= 48) ? fast_sigmoid(g) : fast_tanh(g);
      const int j = l & 15;
      const float ig = __shfl(act, j, 64);
      const float fg = __shfl(act, j + 16, 64);
      const float gt = __shfl(act, j + 32, 64);
      const float og = __shfl(act, j + 48, 64);
      if (l < H_SLICE) {
        c = fg * c + ig * gt;
        const float h = og * fast_tanh(c);
        hshm[slot * H_SLICE + l] = h;  // own-slice shortcut (fp32)
        const unsigned int pkt =
            (((unsigned int)(t + 1) & 0xFFFFu) << 16) |
            (unsigned int)__half_as_ushort(__float2half_rn(h));
        store_pkt(pub + ((t + 1) & 1) * H_DIM + slot * H_SLICE + l, pkt);
      }
    }
    // hshm/red hazards covered by barriers B/C (disjoint index sets).
  }

  // retire dangling probes before their registers can be reused
  asm volatile("s_waitcnt vmcnt(0)" : "+v"(rA), "+v"(rB) :: "memory");

  // ---- slot 0: final projection out = h(T) . Wlin + blin ----
  if (slot == 0) {
    if (poller) {  // gather h(T) (parity T&1 == 0); own slice already fp32
      const unsigned int* p = pub + (T_STEPS & 1) * H_DIM + tid * 4;
      const unsigned int tg = (unsigned int)T_STEPS & 0xFFFFu;
      for (;;) {
        uint32x4 r = load_pkt4(p);
        if (tag_ok(r, tg)) { stage4(hshm + tid * 4, r); break; }
      }
    }
    __syncthreads();
    red[tid] = hshm[2 * tid] * Wlin[2 * tid] +
               hshm[2 * tid + 1] * Wlin[2 * tid + 1];
    __syncthreads();
    if (w == 0) {
      float s = red[l] + red[64 + l] + red[128 + l] + red[192 + l];
      #pragma unroll
      for (int off = 32; off > 0; off >>= 1) s += __shfl_down(s, off, 64);
      if (l == 0) out[0] = s + blin[0];
    }
  }
}

extern "C" void kernel_launch(void* const* d_in, const int* in_sizes, int n_in,
                              void* d_out, int out_size, void* d_ws, size_t ws_size,
                              hipStream_t stream) {
  const float* x    = (const float*)d_in[0];
  const float* Wih  = (const float*)d_in[1];
  const float* Whh  = (const float*)d_in[2];
  const float* bih  = (const float*)d_in[3];
  const float* bhh  = (const float*)d_in[4];
  const float* Wlin = (const float*)d_in[5];
  const float* blin = (const float*)d_in[6];
  float* out = (float*)d_out;

  unsigned int* pub = (unsigned int*)d_ws;  // [2][512] u32 = 4096 B

  // d_ws re-poisoned 0xAA before every timed call; zeroed pub encodes
  // (tag=0, h=0) = the initial hidden state.
  hipMemsetAsync(d_ws, 0, 4096, stream);
  hipLaunchKernelGGL(lstm_scan_kernel, dim3(SLOTS), dim3(256), 0, stream,
                     x, Wih, Whh, bih, bhh, Wlin, blin, out, pub);
}